// Round 6
// baseline (166.543 us; speedup 1.0000x reference)
//
#include <hip/hip_runtime.h>
#include <math.h>

// Fused QWZ deformation + HS-distance kernel, v7b: row-streaming, fully
// sequential access. (v7 + compile fix: __builtin_nontemporal_store needs a
// native vector type, not HIP_vector_type -- use ext_vector_type(4).)
// Evidence: v2/v3/v5/v6 (tiles, any schedule) all pin at ~52-57us /
// 2.8-3.1 TB/s fabric traffic; L3-resident dispatches equally slow; no pipe
// saturated. Shared property: short scattered runs (132-264B per halo row per
// array). v7 makes every stream long: each block owns a 1024x4 row band, walks
// rows; per array per row it reads 4KB contiguous and writes 4KB contiguous
// per plane (dwordx4). No LDS: i+1 = rolling register window, j+1 =
// __shfl_down + lane-63 redundant site, angle n-1 = __shfl_up + lane-0 scalar.
// Raw rows register-double-buffered (loads one full row-step ahead).
#define MESHW 1024   // columns per block
#define RPB   4      // output rows per block
#define TPB   256    // threads; each owns 4 consecutive cols

typedef float vfloat4 __attribute__((ext_vector_type(4)));

struct Raw {
    float4 th, ph, ps;     // theta/phi/psi[n0..n0+3]: angle src for sites n0+1..n0+4
    float4 s01, s23;       // sre sites n0..n0+3 (2 sites per float4)
    float4 i01, i23;       // sim sites n0..n0+3
    float2 er, ei;         // lane-63 extra site (col+4) spinor
    float  eth, eph, eps;  // lane-0: angles for site n0 (n0-1); lane-63: wrap-case angles
    int    n0;             // flat index of first owned site this row
    int    nx;             // lane-63 extra site flat index
};

__device__ __forceinline__ void load_row(Raw& B, int r, int cj, int mesh, int N,
    const float* __restrict__ theta, const float* __restrict__ phi,
    const float* __restrict__ psi, const float2* __restrict__ sre,
    const float2* __restrict__ sim, int lane)
{
    if (r >= mesh) r -= mesh;               // halo row wrap
    const int n0 = r * mesh + cj;           // n0 % 4 == 0 -> 16B aligned
    B.n0 = n0;

    if (n0 + 4 < N) {
        B.th = *(const float4*)(theta + n0);
        B.ph = *(const float4*)(phi   + n0);
        B.ps = *(const float4*)(psi   + n0);
    } else {                                 // last quad: theta has N-1 elems
        B.th = make_float4(theta[n0], theta[n0 + 1], theta[n0 + 2], 0.f);
        B.ph = make_float4(phi[n0],   phi[n0 + 1],   phi[n0 + 2],   0.f);
        B.ps = make_float4(psi[n0],   psi[n0 + 1],   psi[n0 + 2],   0.f);
    }
    const float4* sreq = (const float4*)sre;
    const float4* simq = (const float4*)sim;
    B.s01 = sreq[n0 >> 1];  B.s23 = sreq[(n0 >> 1) + 1];
    B.i01 = simq[n0 >> 1];  B.i23 = simq[(n0 >> 1) + 1];

    if (lane == 0) {                         // angle for site n0 (prev wave's col)
        int a = (n0 > 0) ? n0 - 1 : 0;       // origin's value unused
        B.eth = theta[a]; B.eph = phi[a]; B.eps = psi[a];
    }
    if (lane == 63) {                        // redundant overlap site at col+4
        int jn = cj + 4; if (jn >= mesh) jn -= mesh;
        int nx = r * mesh + jn;
        B.nx = nx;
        B.er = sre[nx]; B.ei = sim[nx];
        if (jn == 0) {                       // wrapped: angles not in our quad
            int a = (nx > 0) ? nx - 1 : 0;
            B.eth = theta[a]; B.eph = phi[a]; B.eps = psi[a];
        }
    }
}

__device__ __forceinline__ float4 deform1(float th, float ph, float ps,
                                          float2 r, float2 im, bool origin) {
    float st, ct, sp, cp, sq, cq;
    __sincosf(th, &st, &ct);
    __sincosf(ph, &sp, &cp);
    __sincosf(ps, &sq, &cq);
    float a = ct * cp;   // su_re diag
    float b = st * cq;   // su_re off-diag
    float c = ct * sp;   // su_im diag
    float d = st * sq;   // su_im off-diag
    float4 d4;
    d4.x = a * r.x - b * r.y - c * im.x + d * im.y;
    d4.y = b * r.x + a * r.y + d * im.x + c * im.y;
    d4.z = a * im.x - b * im.y + c * r.x - d * r.y;
    d4.w = b * im.x + a * im.y - d * r.x - c * r.y;
    if (origin) d4 = make_float4(r.x, r.y, im.x, im.y);  // site 0 undeformed
    return d4;
}

__device__ __forceinline__ void deform_row(const Raw& B, float4 A[4],
                                           float4& Aext, int lane)
{
    // angle for site n0: previous lane's th.w (contiguous cols within a wave)
    float thm = __shfl_up(B.th.w, 1, 64);
    float phm = __shfl_up(B.ph.w, 1, 64);
    float psm = __shfl_up(B.ps.w, 1, 64);
    if (lane == 0) { thm = B.eth; phm = B.eph; psm = B.eps; }

    A[0] = deform1(thm,    phm,    psm,
                   make_float2(B.s01.x, B.s01.y), make_float2(B.i01.x, B.i01.y),
                   B.n0 == 0);
    A[1] = deform1(B.th.x, B.ph.x, B.ps.x,
                   make_float2(B.s01.z, B.s01.w), make_float2(B.i01.z, B.i01.w),
                   false);
    A[2] = deform1(B.th.y, B.ph.y, B.ps.y,
                   make_float2(B.s23.x, B.s23.y), make_float2(B.i23.x, B.i23.y),
                   false);
    A[3] = deform1(B.th.z, B.ph.z, B.ps.z,
                   make_float2(B.s23.z, B.s23.w), make_float2(B.i23.z, B.i23.w),
                   false);
    if (lane == 63) {                        // overlap site col+4
        float et = B.th.w, ep = B.ph.w, eq = B.ps.w;   // angle idx n0+3 = nx-1
        if (B.nx != B.n0 + 4) { et = B.eth; ep = B.eph; eq = B.eps; }  // wrapped
        Aext = deform1(et, ep, eq, B.er, B.ei, B.nx == 0);
    }
}

__device__ __forceinline__ float hsdist(float4 A, float4 B) {
    float rr = A.x * B.x + A.y * B.y + A.z * B.z + A.w * B.w;
    float ri = A.x * B.z + A.y * B.w - A.z * B.x - A.w * B.y;
    return sqrtf(fabsf(1.0f - rr * rr - ri * ri));
}

__device__ __forceinline__ float4 shift_in(const float4 A0, const float4 Aext,
                                           int lane)
{
    float4 n;
    n.x = __shfl_down(A0.x, 1, 64);
    n.y = __shfl_down(A0.y, 1, 64);
    n.z = __shfl_down(A0.z, 1, 64);
    n.w = __shfl_down(A0.w, 1, 64);
    if (lane == 63) n = Aext;               // cross-wave / seam overlap site
    return n;
}

__device__ __forceinline__ void nt_store4(float* p, float a, float b,
                                          float c, float d)
{
    vfloat4 q = {a, b, c, d};
    __builtin_nontemporal_store(q, (vfloat4*)p);
}

__device__ __forceinline__ void emit_row(const float4 A[4], const float4 Aext,
    const float4 Bv[4], const float4 Bext, int row, int cj, int mesh, int N,
    float* __restrict__ out, int lane)
{
    const float4 An = shift_in(A[0], Aext, lane);    // deformed (row, col+4)
    const float4 Bn = shift_in(Bv[0], Bext, lane);   // deformed (row+1, col+4)

    const int site = row * mesh + cj;
    nt_store4(out + site,
              hsdist(A[0], A[1]), hsdist(A[1], A[2]),
              hsdist(A[2], A[3]), hsdist(A[3], An));
    nt_store4(out + N + site,
              hsdist(A[0], Bv[0]), hsdist(A[1], Bv[1]),
              hsdist(A[2], Bv[2]), hsdist(A[3], Bv[3]));
    nt_store4(out + 2 * N + site,
              hsdist(A[0], Bv[1]), hsdist(A[1], Bv[2]),
              hsdist(A[2], Bv[3]), hsdist(A[3], Bn));
}

__global__ __launch_bounds__(TPB, 4) void qwz_deform_dirichlet_kernel(
    const float* __restrict__ theta,
    const float* __restrict__ phi,
    const float* __restrict__ psi,
    const float2* __restrict__ sre,
    const float2* __restrict__ sim,
    float* __restrict__ out,          // [3, mesh, mesh]
    int mesh)
{
    const int N = mesh * mesh;
    const int tid  = threadIdx.x;
    const int lane = tid & 63;
    const int cj = blockIdx.x * MESHW + 4 * tid;   // first owned column
    const int r0 = blockIdx.y * RPB;

    Raw ra, rb;
    float4 A[4], B[4], Aext, Bext;

    // prologue: rows r0 and r0+1 issued back-to-back, then deform r0
    load_row(ra, r0,     cj, mesh, N, theta, phi, psi, sre, sim, lane);
    load_row(rb, r0 + 1, cj, mesh, N, theta, phi, psi, sre, sim, lane);
    deform_row(ra, A, Aext, lane);

    // k=0: prefetch r0+2, finish r0+1, emit row r0
    load_row(ra, r0 + 2, cj, mesh, N, theta, phi, psi, sre, sim, lane);
    deform_row(rb, B, Bext, lane);
    emit_row(A, Aext, B, Bext, r0, cj, mesh, N, out, lane);
    A[0] = B[0]; A[1] = B[1]; A[2] = B[2]; A[3] = B[3]; Aext = Bext;

    // k=1
    load_row(rb, r0 + 3, cj, mesh, N, theta, phi, psi, sre, sim, lane);
    deform_row(ra, B, Bext, lane);
    emit_row(A, Aext, B, Bext, r0 + 1, cj, mesh, N, out, lane);
    A[0] = B[0]; A[1] = B[1]; A[2] = B[2]; A[3] = B[3]; Aext = Bext;

    // k=2 (halo row r0+4 may wrap to 0)
    load_row(ra, r0 + 4, cj, mesh, N, theta, phi, psi, sre, sim, lane);
    deform_row(rb, B, Bext, lane);
    emit_row(A, Aext, B, Bext, r0 + 2, cj, mesh, N, out, lane);
    A[0] = B[0]; A[1] = B[1]; A[2] = B[2]; A[3] = B[3]; Aext = Bext;

    // k=3
    deform_row(ra, B, Bext, lane);
    emit_row(A, Aext, B, Bext, r0 + 3, cj, mesh, N, out, lane);
}

extern "C" void kernel_launch(void* const* d_in, const int* in_sizes, int n_in,
                              void* d_out, int out_size, void* d_ws, size_t ws_size,
                              hipStream_t stream) {
    const float* theta = (const float*)d_in[0];
    const float* phi   = (const float*)d_in[1];
    const float* psi   = (const float*)d_in[2];
    const float2* sre  = (const float2*)d_in[3];
    const float2* sim  = (const float2*)d_in[4];
    float* out = (float*)d_out;

    int N = in_sizes[0] + 1;                       // theta has N-1 elements
    int mesh = (int)(sqrt((double)N) + 0.5);       // 2048

    dim3 grid(mesh / MESHW, mesh / RPB);           // (2, 512) = 1024 blocks
    dim3 block(TPB);
    qwz_deform_dirichlet_kernel<<<grid, block, 0, stream>>>(
        theta, phi, psi, sre, sim, out, mesh);
}